// Round 12
// baseline (270.850 us; speedup 1.0000x reference)
//
#include <hip/hip_runtime.h>
#include <hip/hip_bf16.h>
#include <math.h>

#define NTOK 8192
#define HID  1024
#define ISZ  256
#define NEXP 16
#define NBIG 4096  // NEXP*ISZ

typedef __attribute__((ext_vector_type(8))) short bf16x8;
typedef __attribute__((ext_vector_type(4))) float f32x4;

#define MFMA16(a, b, c) __builtin_amdgcn_mfma_f32_16x16x32_bf16(a, b, c, 0, 0, 0)

__device__ __forceinline__ unsigned short f2bf(float f) {
  unsigned u = __float_as_uint(f);
  u += 0x7fff + ((u >> 16) & 1);
  return (unsigned short)(u >> 16);
}

__device__ __forceinline__ void async16(void* l, const void* g) {
  __builtin_amdgcn_global_load_lds(
      (const __attribute__((address_space(1))) unsigned int*)g,
      (__attribute__((address_space(3))) unsigned int*)l, 16, 0, 0);
}

// ---------------- sim_matrix column inverse norms ----------------
__global__ void simnorm_kernel(const float* __restrict__ sm, float* __restrict__ inv_smn) {
  __shared__ float red[16][17];
  int t = threadIdx.x;
  int e = t & 15, g = t >> 4;
  float ss = 0.f;
  for (int c = g; c < HID; c += 16) {
    float v = sm[c * NEXP + e];
    ss += v * v;
  }
  red[e][g] = ss;
  __syncthreads();
  if (t < 16) {
    float s = 0.f;
    #pragma unroll
    for (int i = 0; i < 16; i++) s += red[t][i];
    inv_smn[t] = 1.f / fmaxf(sqrtf(s), 1e-12f);
  }
}

// ---------------- gate: scores, k, routing weights, bf16 cast of x ----------------
__global__ __launch_bounds__(256)
void gate_kernel(const float* __restrict__ x, const float* __restrict__ sm,
                 const float* __restrict__ thr, const float* __restrict__ inv_smn,
                 float* __restrict__ scores_out, float* __restrict__ k_out,
                 float* __restrict__ rw_out, unsigned short* __restrict__ xb_out) {
  const int n = blockIdx.x;
  const int t = threadIdx.x;
  const int lane = t & 63, wave = t >> 6;
  const float* xr = x + (size_t)n * HID;

  float p[16];
  #pragma unroll
  for (int e = 0; e < 16; e++) p[e] = 0.f;
  float ss = 0.f;

  #pragma unroll
  for (int q = 0; q < 4; q++) {
    int c = t + q * 256;
    float v = xr[c];
    ss += v * v;
    xb_out[(size_t)n * HID + c] = f2bf(v);
    const float4* smr = (const float4*)(sm + (size_t)c * NEXP);
    float4 s0 = smr[0], s1 = smr[1], s2 = smr[2], s3 = smr[3];
    p[0] += v * s0.x;  p[1] += v * s0.y;  p[2] += v * s0.z;  p[3] += v * s0.w;
    p[4] += v * s1.x;  p[5] += v * s1.y;  p[6] += v * s1.z;  p[7] += v * s1.w;
    p[8] += v * s2.x;  p[9] += v * s2.y;  p[10] += v * s2.z; p[11] += v * s2.w;
    p[12] += v * s3.x; p[13] += v * s3.y; p[14] += v * s3.z; p[15] += v * s3.w;
  }

  #pragma unroll
  for (int off = 32; off > 0; off >>= 1) {
    ss += __shfl_down(ss, off, 64);
    #pragma unroll
    for (int e = 0; e < 16; e++) p[e] += __shfl_down(p[e], off, 64);
  }

  __shared__ float red[4][17];
  __shared__ float sc[16];
  if (lane == 0) {
    red[wave][0] = ss;
    #pragma unroll
    for (int e = 0; e < 16; e++) red[wave][1 + e] = p[e];
  }
  __syncthreads();

  if (t < 16) {
    float d = red[0][1 + t] + red[1][1 + t] + red[2][1 + t] + red[3][1 + t];
    float ssum = red[0][0] + red[1][0] + red[2][0] + red[3][0];
    float inv_x = 1.f / fmaxf(sqrtf(ssum), 1e-12f);
    float s = d * inv_x * inv_smn[t];
    scores_out[(size_t)n * 16 + t] = s;
    sc[t] = s;
  }
  __syncthreads();

  if (t < 16) {
    float thrv = thr[0];
    float s = sc[t];
    bool act = s > thrv;
    float m = act ? s : -INFINITY;
    int cnt = act ? 1 : 0;
    #pragma unroll
    for (int off = 8; off > 0; off >>= 1) {
      m = fmaxf(m, __shfl_xor(m, off, 16));
      cnt += __shfl_xor(cnt, off, 16);
    }
    float pv;
    if (cnt > 0) pv = act ? expf(s - m) : 0.f;
    else         pv = 1.f;
    float sum = pv;
    #pragma unroll
    for (int off = 8; off > 0; off >>= 1) sum += __shfl_xor(sum, off, 16);
    rw_out[(size_t)n * 16 + t] = pv / sum;
    if (t == 0) k_out[n] = (float)cnt;
  }
}

// ---------------- transpose + bf16 cast (row-major out; used for w2) ----------------
__global__ __launch_bounds__(256)
void transpose_cast_kernel(const float* __restrict__ src, unsigned short* __restrict__ dst,
                           int R, int C, int dstride, int e_src_stride, int e_dst_mult) {
  __shared__ float tile[32][33];
  const int e = blockIdx.z;
  const int r0 = blockIdx.y * 32, c0 = blockIdx.x * 32;
  const int tx = threadIdx.x & 31, ty = threadIdx.x >> 5;
  const float* s = src + (size_t)e * e_src_stride;
  #pragma unroll
  for (int q = 0; q < 4; q++) {
    int r = r0 + ty + q * 8;
    tile[ty + q * 8][tx] = s[(size_t)r * C + c0 + tx];
  }
  __syncthreads();
  unsigned short* d = dst + (size_t)e * e_dst_mult;
  #pragma unroll
  for (int q = 0; q < 4; q++) {
    int cc = c0 + ty + q * 8;
    int r  = r0 + tx;
    d[(size_t)cc * dstride + r] = f2bf(tile[tx][ty + q * 8]);
  }
}

// ---------- w1 -> W1F fragment-major: seg(rowblk, k>>5, kg, lr) of 8 elems ----------
// element addr = ((rowblk*32 + (k>>5))*64 + ((k>>3)&3)*16 + lr)*8 + (k&7)
// rowblk = (e*256 + inter)>>4, lr = inter&15.
__global__ __launch_bounds__(256)
void transpose_cast_frag(const float* __restrict__ w1, unsigned short* __restrict__ W1F) {
  __shared__ float tile[32][33];
  const int e = blockIdx.z;
  const int r0 = blockIdx.y * 32, c0 = blockIdx.x * 32;  // r0: hidden(k), c0: inter
  const int tx = threadIdx.x & 31, ty = threadIdx.x >> 5;
  const float* s = w1 + (size_t)e * (HID * ISZ);
  #pragma unroll
  for (int q = 0; q < 4; q++) {
    int r = r0 + ty + q * 8;
    tile[ty + q * 8][tx] = s[(size_t)r * ISZ + c0 + tx];   // tile[k_local][inter_local]
  }
  __syncthreads();
  const int t = threadIdx.x;
  if (t < 128) {
    const int sc = t & 31, gg = t >> 5;   // inter_local, k-octet
    const int gi = e * ISZ + c0 + sc;     // global inter index (B row)
    const int k  = r0 + gg * 8;           // global hidden index
    const int rowblk = gi >> 4, lr = gi & 15;
    bf16x8 v;
    #pragma unroll
    for (int j = 0; j < 8; j++) v[j] = (short)f2bf(tile[gg * 8 + j][sc]);
    size_t base = ((size_t)rowblk * 2048 + (size_t)(k >> 5) * 64 + ((k >> 3) & 3) * 16 + lr) * 8;
    *(bf16x8*)(W1F + base) = v;
  }
}

// ---------- Xb (row-major) -> XbF fragment-major, LDS pivot, coalesced both sides ----------
__global__ __launch_bounds__(256)
void repack_frag(const unsigned short* __restrict__ Xb, unsigned short* __restrict__ XbF) {
  __shared__ unsigned short lds2[16 * 1032];
  const int b = blockIdx.x;          // rowblk in [0,512)
  const int t = threadIdx.x;
  #pragma unroll
  for (int j = 0; j < 8; j++) {
    int s = t + 256 * j;             // [0,2048): 16-B segments
    int row = s >> 7, kseg = s & 127;
    bf16x8 v = *(const bf16x8*)(Xb + ((size_t)(b * 16 + row)) * HID + kseg * 8);
    *(bf16x8*)(&lds2[row * 1032 + kseg * 8]) = v;
  }
  __syncthreads();
  #pragma unroll
  for (int j = 0; j < 8; j++) {
    int s2 = t + 256 * j;            // output segment index
    int l = s2 & 63, kb = s2 >> 6;   // lane, (kt*2+kk)
    int row = l & 15, k = kb * 32 + (l >> 4) * 8;
    bf16x8 v = *(const bf16x8*)(&lds2[row * 1032 + k]);
    *(bf16x8*)(XbF + (size_t)b * 16384 + (size_t)s2 * 8) = v;
  }
}

// ========== GEMM1: 256x256, 8 waves, NO LDS, fragment-direct from L1/L2 ==========
// A (XbF) and B (W1F) pre-packed fragment-major: one wave load = 64 lanes x 16 B
// contiguous. No barriers, no LDS: reg ping-pong (static sets a0/b0, a1/b1) +
// 2 waves/SIMD TLP hide L2 latency. Race-free by construction.
template <int KO, int NBN>   // KO = K/32 (kt*2+kk slots)
__global__ __launch_bounds__(512, 2)
void gemm1_frag(const unsigned short* __restrict__ XbF, const unsigned short* __restrict__ W1F,
                unsigned short* __restrict__ Cb, const float* __restrict__ rw) {
  const int tid = threadIdx.x;
  const int lane = tid & 63, wid = tid >> 6;
  const int wm = wid >> 2, wn = wid & 3;   // wave tile 128x64
  const int lr = lane & 15;

  const int nwg = gridDim.x, cpx = nwg >> 3;
  const int wg = (blockIdx.x & 7) * cpx + (blockIdx.x >> 3);
  const int bm = wg / NBN, bn = wg % NBN;

  const unsigned short* Ab = XbF + ((size_t)(bm * 16 + wm * 8) * 2048 + lane) * 8;
  const unsigned short* Bb = W1F + ((size_t)(bn * 16 + wn * 4) * 2048 + lane) * 8;

  f32x4 acc[8][4];
  #pragma unroll
  for (int m = 0; m < 8; m++)
    #pragma unroll
    for (int n = 0; n < 4; n++) acc[m][n] = (f32x4){0.f, 0.f, 0.f, 0.f};

  bf16x8 a0[8], b0[4], a1[8], b1[4];
  #pragma unroll
  for (int mf = 0; mf < 8; mf++) a0[mf] = *(const bf16x8*)(Ab + mf * 16384);
  #pragma unroll
  for (int nf = 0; nf < 4; nf++) b0[nf] = *(const bf16x8*)(Bb + nf * 16384);

  #pragma unroll 1
  for (int ko = 0; ko < KO; ko += 2) {
    const int k1 = ko + 1;
    const int k2 = (ko + 2) & (KO - 1);   // wraps to 0 on last iter (harmless reload)
    #pragma unroll
    for (int mf = 0; mf < 8; mf++) a1[mf] = *(const bf16x8*)(Ab + mf * 16384 + k1 * 512);
    #pragma unroll
    for (int nf = 0; nf < 4; nf++) b1[nf] = *(const bf16x8*)(Bb + nf * 16384 + k1 * 512);
    #pragma unroll
    for (int mf = 0; mf < 8; mf++)
      #pragma unroll
      for (int nf = 0; nf < 4; nf++)
        acc[mf][nf] = MFMA16(a0[mf], b0[nf], acc[mf][nf]);
    #pragma unroll
    for (int mf = 0; mf < 8; mf++) a0[mf] = *(const bf16x8*)(Ab + mf * 16384 + k2 * 512);
    #pragma unroll
    for (int nf = 0; nf < 4; nf++) b0[nf] = *(const bf16x8*)(Bb + nf * 16384 + k2 * 512);
    #pragma unroll
    for (int mf = 0; mf < 8; mf++)
      #pragma unroll
      for (int nf = 0; nf < 4; nf++)
        acc[mf][nf] = MFMA16(a1[mf], b1[nf], acc[mf][nf]);
  }

  // epilogue: C/D layout col=lane&15, row=(lane>>4)*4+j (verified)
  const int jr = (lane >> 4) * 4;
  float wrow[8][4];
  #pragma unroll
  for (int m = 0; m < 8; m++)
    #pragma unroll
    for (int j = 0; j < 4; j++)
      wrow[m][j] = rw[(size_t)(bm * 256 + wm * 128 + m * 16 + jr + j) * 16 + bn];
  #pragma unroll
  for (int m = 0; m < 8; m++) {
    #pragma unroll
    for (int n = 0; n < 4; n++) {
      int col = bn * 256 + wn * 64 + n * 16 + lr;
      #pragma unroll
      for (int j = 0; j < 4; j++) {
        int r = bm * 256 + wm * 128 + m * 16 + jr + j;
        float v = acc[m][n][j];
        float g = 0.7978845608f * (v + 0.044715f * v * v * v);
        float e = __expf(2.f * g);
        float th = 1.f - 2.f / (e + 1.f);   // tanh(g), inf-safe
        float ge = 0.5f * v * (1.f + th);
        Cb[(size_t)r * NBIG + col] = f2bf(ge * wrow[m][j]);
      }
    }
  }
}

// ============ GEMM2: 128x256, 8-wave (2x4), 2-phase/K-tile (r6-verified) ============
#define G2PHASE(CK, STG, WAIT_)                                                \
  {                                                                            \
    bf16x8 afr[4], bfr[4];                                                     \
    _Pragma("unroll")                                                          \
    for (int ml = 0; ml < 4; ml++)                                             \
      afr[ml] = *(const bf16x8*)(bufA + wmo + ml*2048 + lro + (CK));           \
    _Pragma("unroll")                                                          \
    for (int nl = 0; nl < 4; nl++)                                             \
      bfr[nl] = *(const bf16x8*)(bufB + wno + nl*2048 + lro + (CK));           \
    if (STG) {                                                                 \
      _Pragma("unroll")                                                        \
      for (int i = 0; i < 2; i++)                                              \
        async16(ldsAn + o16[i], Ag + (size_t)aRow[i]*K + kn + aCol[i]);        \
      _Pragma("unroll")                                                        \
      for (int i = 0; i < 4; i++)                                              \
        async16(ldsBn + o16b[i], Bg + (size_t)bRow[i]*K + kn + bCol[i]);       \
    }                                                                          \
    __builtin_amdgcn_sched_barrier(0);                                         \
    __builtin_amdgcn_s_barrier();                                              \
    asm volatile("s_waitcnt lgkmcnt(0)" ::: "memory");                         \
    __builtin_amdgcn_sched_barrier(0);                                         \
    __builtin_amdgcn_s_setprio(1);                                             \
    _Pragma("unroll")                                                          \
    for (int m4 = 0; m4 < 4; m4++)                                             \
      _Pragma("unroll")                                                        \
      for (int n4 = 0; n4 < 4; n4++)                                           \
        acc[m4][n4] = MFMA16(afr[m4], bfr[n4], acc[m4][n4]);                   \
    __builtin_amdgcn_s_setprio(0);                                             \
    __builtin_amdgcn_sched_barrier(0);                                         \
    if (WAIT_) { asm volatile("s_waitcnt vmcnt(0)" ::: "memory"); }            \
    __builtin_amdgcn_s_barrier();                                              \
    __builtin_amdgcn_sched_barrier(0);                                         \
  }

template <int K>
__global__ __launch_bounds__(512, 2)
void gemm2_k(const unsigned short* __restrict__ A, const unsigned short* __restrict__ B,
             float* __restrict__ Cf) {
  __shared__ __align__(1024) char lds[98304];
  constexpr int NT = K / 64;
  const int tid = threadIdx.x;
  const int lane = tid & 63, wid = tid >> 6;
  const int wm = wid >> 2, wn = wid & 3;   // 2 x 4 waves, wave tile 64x64
  const int lr = lane & 15;

  const int wg = (blockIdx.x & 7) * 32 + (blockIdx.x >> 3);  // nwg=256
  const int bm = wg >> 2, bn = wg & 3;

  const int swz = (lr & 7) << 4;
  const int colk0 = ((lane >> 4) * 16) ^ swz;
  const int colk1 = (64 + (lane >> 4) * 16) ^ swz;
  const int wmo = wm * 8192, wno = wn * 8192, lro = lr * 128;

  int aRow[2], aCol[2], o16[2];
  int bRow[4], bCol[4], o16b[4];
  #pragma unroll
  for (int i = 0; i < 2; i++) {
    int o = (i * 512 + tid) * 16;
    o16[i] = o;
    int r = o >> 7, cb = o & 127;
    aRow[i] = r; aCol[i] = (cb ^ ((r & 7) << 4)) >> 1;
  }
  #pragma unroll
  for (int i = 0; i < 4; i++) {
    int o = (i * 512 + tid) * 16;
    o16b[i] = o;
    int r = o >> 7, cb = o & 127;
    bRow[i] = r; bCol[i] = (cb ^ ((r & 7) << 4)) >> 1;
  }

  const unsigned short* Ag = A + (size_t)bm * 128 * K;
  const unsigned short* Bg = B + (size_t)bn * 256 * K;

  f32x4 acc[4][4];
  #pragma unroll
  for (int m = 0; m < 4; m++)
    #pragma unroll
    for (int n = 0; n < 4; n++) acc[m][n] = (f32x4){0.f, 0.f, 0.f, 0.f};

  #pragma unroll
  for (int i = 0; i < 2; i++) async16(lds + o16[i],          Ag + (size_t)aRow[i] * K + aCol[i]);
  #pragma unroll
  for (int i = 0; i < 4; i++) async16(lds + 32768 + o16b[i], Bg + (size_t)bRow[i] * K + bCol[i]);
  asm volatile("s_waitcnt vmcnt(0)" ::: "memory");
  __builtin_amdgcn_s_barrier();

  #pragma unroll 1
  for (int t = 0; t < NT; t += 2) {
    {
      const char* bufA = lds;
      const char* bufB = lds + 32768;
      char* ldsAn = lds + 16384;
      char* ldsBn = lds + 32768 + 32768;
      const int kn = ((t + 1) & (NT - 1)) << 6;
      G2PHASE(colk0, 1, 0)
      G2PHASE(colk1, 0, 1)
    }
    {
      const char* bufA = lds + 16384;
      const char* bufB = lds + 32768 + 32768;
      char* ldsAn = lds;
      char* ldsBn = lds + 32768;
      const int kn = ((t + 2) & (NT - 1)) << 6;
      G2PHASE(colk0, 1, 0)
      G2PHASE(colk1, 0, 1)
    }
  }

  asm volatile("s_waitcnt vmcnt(0)" ::: "memory");

  const int jr = (lane >> 4) * 4;
  #pragma unroll
  for (int m = 0; m < 4; m++) {
    #pragma unroll
    for (int n = 0; n < 4; n++) {
      int col = bn * 256 + wn * 64 + n * 16 + lr;
      #pragma unroll
      for (int j = 0; j < 4; j++) {
        int r = bm * 128 + wm * 64 + m * 16 + jr + j;
        Cf[(size_t)r * HID + col] = acc[m][n][j];
      }
    }
  }
}

extern "C" void kernel_launch(void* const* d_in, const int* in_sizes, int n_in,
                              void* d_out, int out_size, void* d_ws, size_t ws_size,
                              hipStream_t stream) {
  const float* x   = (const float*)d_in[0];
  const float* sm  = (const float*)d_in[1];
  const float* thr = (const float*)d_in[2];
  const float* w1  = (const float*)d_in[3];
  const float* w2  = (const float*)d_in[4];

  float* out_final  = (float*)d_out;
  float* out_scores = out_final + (size_t)NTOK * HID;
  float* out_k      = out_scores + (size_t)NTOK * NEXP;

  char* ws = (char*)d_ws;
  size_t off = 0;
  float* inv_smn = (float*)(ws + off); off += 256;
  float* rwbuf   = (float*)(ws + off); off += (size_t)NTOK * NEXP * 4;
  unsigned short* Xb  = (unsigned short*)(ws + off); off += (size_t)NTOK * HID * 2;
  unsigned short* XbF = (unsigned short*)(ws + off); off += (size_t)NTOK * HID * 2;
  unsigned short* W1F = (unsigned short*)(ws + off); off += (size_t)NBIG * HID * 2;
  unsigned short* W2T = (unsigned short*)(ws + off); off += (size_t)HID * NBIG * 2;
  unsigned short* H   = (unsigned short*)(ws + off); off += (size_t)NTOK * NBIG * 2;

  simnorm_kernel<<<1, 256, 0, stream>>>(sm, inv_smn);
  gate_kernel<<<NTOK, 256, 0, stream>>>(x, sm, thr, inv_smn, out_scores, out_k, rwbuf, Xb);
  // Xb row-major -> fragment-major
  repack_frag<<<512, 256, 0, stream>>>(Xb, XbF);
  // w1 -> W1F fragment-major
  transpose_cast_frag<<<dim3(ISZ / 32, HID / 32, NEXP), 256, 0, stream>>>(w1, W1F);
  // w2 -> W2T row-major B^T (for r6-verified GEMM2)
  transpose_cast_kernel<<<dim3(HID / 32, ISZ / 32, NEXP), 256, 0, stream>>>(
      w2, W2T, ISZ, HID, NBIG, ISZ * HID, ISZ);

  // H = gelu(XbF @ W1F^T) * rw   [8192 x 4096], 512 blocks, no-LDS fragment GEMM
  gemm1_frag<HID / 32, 16><<<512, 512, 0, stream>>>(XbF, W1F, H, rwbuf);
  // final = H @ W2T^T            [8192 x 1024], 256 blocks (r6-verified)
  gemm2_k<NBIG><<<256, 512, 0, stream>>>(H, W2T, out_final);
}

// Round 13
// 226.757 us; speedup vs baseline: 1.1944x; 1.1944x over previous
//
#include <hip/hip_runtime.h>
#include <hip/hip_bf16.h>
#include <math.h>

#define NTOK 8192
#define HID  1024
#define ISZ  256
#define NEXP 16
#define NBIG 4096  // NEXP*ISZ

typedef __attribute__((ext_vector_type(8))) short bf16x8;
typedef __attribute__((ext_vector_type(4))) float f32x4;

#define MFMA16(a, b, c) __builtin_amdgcn_mfma_f32_16x16x32_bf16(a, b, c, 0, 0, 0)

__device__ __forceinline__ unsigned short f2bf(float f) {
  unsigned u = __float_as_uint(f);
  u += 0x7fff + ((u >> 16) & 1);
  return (unsigned short)(u >> 16);
}

__device__ __forceinline__ void async16(void* l, const void* g) {
  __builtin_amdgcn_global_load_lds(
      (const __attribute__((address_space(1))) unsigned int*)g,
      (__attribute__((address_space(3))) unsigned int*)l, 16, 0, 0);
}

// ---------------- sim_matrix column inverse norms ----------------
__global__ void simnorm_kernel(const float* __restrict__ sm, float* __restrict__ inv_smn) {
  __shared__ float red[16][17];
  int t = threadIdx.x;
  int e = t & 15, g = t >> 4;
  float ss = 0.f;
  for (int c = g; c < HID; c += 16) {
    float v = sm[c * NEXP + e];
    ss += v * v;
  }
  red[e][g] = ss;
  __syncthreads();
  if (t < 16) {
    float s = 0.f;
    #pragma unroll
    for (int i = 0; i < 16; i++) s += red[t][i];
    inv_smn[t] = 1.f / fmaxf(sqrtf(s), 1e-12f);
  }
}

// ---------------- gate: scores, k, routing weights, bf16 cast of x ----------------
__global__ __launch_bounds__(256)
void gate_kernel(const float* __restrict__ x, const float* __restrict__ sm,
                 const float* __restrict__ thr, const float* __restrict__ inv_smn,
                 float* __restrict__ scores_out, float* __restrict__ k_out,
                 float* __restrict__ rw_out, unsigned short* __restrict__ xb_out) {
  const int n = blockIdx.x;
  const int t = threadIdx.x;
  const int lane = t & 63, wave = t >> 6;
  const float* xr = x + (size_t)n * HID;

  float p[16];
  #pragma unroll
  for (int e = 0; e < 16; e++) p[e] = 0.f;
  float ss = 0.f;

  #pragma unroll
  for (int q = 0; q < 4; q++) {
    int c = t + q * 256;
    float v = xr[c];
    ss += v * v;
    xb_out[(size_t)n * HID + c] = f2bf(v);
    const float4* smr = (const float4*)(sm + (size_t)c * NEXP);
    float4 s0 = smr[0], s1 = smr[1], s2 = smr[2], s3 = smr[3];
    p[0] += v * s0.x;  p[1] += v * s0.y;  p[2] += v * s0.z;  p[3] += v * s0.w;
    p[4] += v * s1.x;  p[5] += v * s1.y;  p[6] += v * s1.z;  p[7] += v * s1.w;
    p[8] += v * s2.x;  p[9] += v * s2.y;  p[10] += v * s2.z; p[11] += v * s2.w;
    p[12] += v * s3.x; p[13] += v * s3.y; p[14] += v * s3.z; p[15] += v * s3.w;
  }

  #pragma unroll
  for (int off = 32; off > 0; off >>= 1) {
    ss += __shfl_down(ss, off, 64);
    #pragma unroll
    for (int e = 0; e < 16; e++) p[e] += __shfl_down(p[e], off, 64);
  }

  __shared__ float red[4][17];
  __shared__ float sc[16];
  if (lane == 0) {
    red[wave][0] = ss;
    #pragma unroll
    for (int e = 0; e < 16; e++) red[wave][1 + e] = p[e];
  }
  __syncthreads();

  if (t < 16) {
    float d = red[0][1 + t] + red[1][1 + t] + red[2][1 + t] + red[3][1 + t];
    float ssum = red[0][0] + red[1][0] + red[2][0] + red[3][0];
    float inv_x = 1.f / fmaxf(sqrtf(ssum), 1e-12f);
    float s = d * inv_x * inv_smn[t];
    scores_out[(size_t)n * 16 + t] = s;
    sc[t] = s;
  }
  __syncthreads();

  if (t < 16) {
    float thrv = thr[0];
    float s = sc[t];
    bool act = s > thrv;
    float m = act ? s : -INFINITY;
    int cnt = act ? 1 : 0;
    #pragma unroll
    for (int off = 8; off > 0; off >>= 1) {
      m = fmaxf(m, __shfl_xor(m, off, 16));
      cnt += __shfl_xor(cnt, off, 16);
    }
    float pv;
    if (cnt > 0) pv = act ? expf(s - m) : 0.f;
    else         pv = 1.f;
    float sum = pv;
    #pragma unroll
    for (int off = 8; off > 0; off >>= 1) sum += __shfl_xor(sum, off, 16);
    rw_out[(size_t)n * 16 + t] = pv / sum;
    if (t == 0) k_out[n] = (float)cnt;
  }
}

// ---------------- transpose + bf16 cast (per-expert 2D transpose) ----------------
__global__ __launch_bounds__(256)
void transpose_cast_kernel(const float* __restrict__ src, unsigned short* __restrict__ dst,
                           int R, int C, int dstride, int e_src_stride, int e_dst_mult) {
  __shared__ float tile[32][33];
  const int e = blockIdx.z;
  const int r0 = blockIdx.y * 32, c0 = blockIdx.x * 32;
  const int tx = threadIdx.x & 31, ty = threadIdx.x >> 5;
  const float* s = src + (size_t)e * e_src_stride;
  #pragma unroll
  for (int q = 0; q < 4; q++) {
    int r = r0 + ty + q * 8;
    tile[ty + q * 8][tx] = s[(size_t)r * C + c0 + tx];
  }
  __syncthreads();
  unsigned short* d = dst + (size_t)e * e_dst_mult;
  #pragma unroll
  for (int q = 0; q < 4; q++) {
    int cc = c0 + ty + q * 8;
    int r  = r0 + tx;
    d[(size_t)cc * dstride + r] = f2bf(tile[tx][ty + q * 8]);
  }
}

// ================== shared fence blocks (r4-verified discipline) ==================
#define FENCE_PRE()                                        \
    __builtin_amdgcn_sched_barrier(0);                     \
    __builtin_amdgcn_s_barrier();                          \
    asm volatile("s_waitcnt lgkmcnt(0)" ::: "memory");     \
    __builtin_amdgcn_sched_barrier(0);                     \
    __builtin_amdgcn_s_setprio(1);

#define FENCE_POST_W4()                                    \
    __builtin_amdgcn_s_setprio(0);                         \
    __builtin_amdgcn_sched_barrier(0);                     \
    asm volatile("s_waitcnt vmcnt(4)" ::: "memory");       \
    __builtin_amdgcn_s_barrier();                          \
    __builtin_amdgcn_sched_barrier(0);

#define FENCE_POST_W6()                                    \
    __builtin_amdgcn_s_setprio(0);                         \
    __builtin_amdgcn_sched_barrier(0);                     \
    asm volatile("s_waitcnt vmcnt(6)" ::: "memory");       \
    __builtin_amdgcn_s_barrier();                          \
    __builtin_amdgcn_sched_barrier(0);

#define FENCE_POST_NOW()                                   \
    __builtin_amdgcn_s_setprio(0);                         \
    __builtin_amdgcn_sched_barrier(0);                     \
    __builtin_amdgcn_s_barrier();                          \
    __builtin_amdgcn_sched_barrier(0);

// =========== GEMM1: 256x256, 8 waves, 4-phase register-reuse (24 reads/tile) ===========
// Quadrants (0,0)->(1,0)->(1,1)->(0,1); a0/a1/b0/b1 each read once per K-tile.
// Stage: P1:{A0',B0'}, P2:{A1',B1'}; waits vmcnt(4) at P1-end (retires A1,B1 of t,
// used P2/P3) and P4-end (retires A0',B0', used t+1.P1). Per-wave invariant
// entering P1: in-flight = {A1(t),B1(t)} = 4. Prologue matches.
#define SU_A0(dst, kn) { async16((dst) + o16[0], Ag + (size_t)aRow[0] * LD + (kn) + aCol[0]); \
                         async16((dst) + o16[1], Ag + (size_t)aRow[1] * LD + (kn) + aCol[1]); }
#define SU_A1(dst, kn) { async16((dst) + 16384 + o16[0], Ag + (size_t)(aRow[0] + 64) * LD + (kn) + aCol[0]); \
                         async16((dst) + 16384 + o16[1], Ag + (size_t)(aRow[1] + 64) * LD + (kn) + aCol[1]); }
#define SU_B0(dst, kn) { async16((dst) + o16[0], Bg + (size_t)bRow[0] * LD + (kn) + bCol[0]); \
                         async16((dst) + o16[1], Bg + (size_t)bRow[1] * LD + (kn) + bCol[1]); }
#define SU_B1(dst, kn) { async16((dst) + 16384 + o16[0], Bg + (size_t)(bRow[0] + 32) * LD + (kn) + bCol[0]); \
                         async16((dst) + 16384 + o16[1], Bg + (size_t)(bRow[1] + 32) * LD + (kn) + bCol[1]); }

#define G1_TILE(bufA, bufB, ldsAn, ldsBn, kn)                                       \
  {                                                                                 \
    bf16x8 a0[4][2], a1[4][2], b0[2][2], b1[2][2];                                  \
    /* P1: (0,0) — read a0(8), b0(4); stage A0',B0' */                              \
    _Pragma("unroll") for (int ml = 0; ml < 4; ml++) {                              \
      a0[ml][0] = *(const bf16x8*)((bufA) + wmo + ml*2048 + lro + colk0);           \
      a0[ml][1] = *(const bf16x8*)((bufA) + wmo + ml*2048 + lro + colk1);           \
    }                                                                               \
    _Pragma("unroll") for (int nl = 0; nl < 2; nl++) {                              \
      b0[nl][0] = *(const bf16x8*)((bufB) + wno + nl*2048 + lro + colk0);           \
      b0[nl][1] = *(const bf16x8*)((bufB) + wno + nl*2048 + lro + colk1);           \
    }                                                                               \
    SU_A0(ldsAn, kn) SU_B0(ldsBn, kn)                                               \
    FENCE_PRE()                                                                     \
    _Pragma("unroll") for (int ml = 0; ml < 4; ml++)                                \
      _Pragma("unroll") for (int nl = 0; nl < 2; nl++) {                            \
        acc[ml][nl] = MFMA16(a0[ml][0], b0[nl][0], acc[ml][nl]);                    \
        acc[ml][nl] = MFMA16(a0[ml][1], b0[nl][1], acc[ml][nl]);                    \
      }                                                                             \
    FENCE_POST_W4()                                                                 \
    /* P2: (1,0) — read a1(8); stage A1',B1' */                                     \
    _Pragma("unroll") for (int ml = 0; ml < 4; ml++) {                              \
      a1[ml][0] = *(const bf16x8*)((bufA) + 16384 + wmo + ml*2048 + lro + colk0);   \
      a1[ml][1] = *(const bf16x8*)((bufA) + 16384 + wmo + ml*2048 + lro + colk1);   \
    }                                                                               \
    SU_A1(ldsAn, kn) SU_B1(ldsBn, kn)                                               \
    FENCE_PRE()                                                                     \
    _Pragma("unroll") for (int ml = 0; ml < 4; ml++)                                \
      _Pragma("unroll") for (int nl = 0; nl < 2; nl++) {                            \
        acc[4 + ml][nl] = MFMA16(a1[ml][0], b0[nl][0], acc[4 + ml][nl]);            \
        acc[4 + ml][nl] = MFMA16(a1[ml][1], b0[nl][1], acc[4 + ml][nl]);            \
      }                                                                             \
    FENCE_POST_NOW()                                                                \
    /* P3: (1,1) — read b1(4) */                                                    \
    _Pragma("unroll") for (int nl = 0; nl < 2; nl++) {                              \
      b1[nl][0] = *(const bf16x8*)((bufB) + 16384 + wno + nl*2048 + lro + colk0);   \
      b1[nl][1] = *(const bf16x8*)((bufB) + 16384 + wno + nl*2048 + lro + colk1);   \
    }                                                                               \
    FENCE_PRE()                                                                     \
    _Pragma("unroll") for (int ml = 0; ml < 4; ml++)                                \
      _Pragma("unroll") for (int nl = 0; nl < 2; nl++) {                            \
        acc[4 + ml][2 + nl] = MFMA16(a1[ml][0], b1[nl][0], acc[4 + ml][2 + nl]);    \
        acc[4 + ml][2 + nl] = MFMA16(a1[ml][1], b1[nl][1], acc[4 + ml][2 + nl]);    \
      }                                                                             \
    FENCE_POST_NOW()                                                                \
    /* P4: (0,1) — no reads */                                                      \
    FENCE_PRE()                                                                     \
    _Pragma("unroll") for (int ml = 0; ml < 4; ml++)                                \
      _Pragma("unroll") for (int nl = 0; nl < 2; nl++) {                            \
        acc[ml][2 + nl] = MFMA16(a0[ml][0], b1[nl][0], acc[ml][2 + nl]);            \
        acc[ml][2 + nl] = MFMA16(a0[ml][1], b1[nl][1], acc[ml][2 + nl]);            \
      }                                                                             \
    FENCE_POST_W4()                                                                 \
  }

template <int KEXT, int LD, int NBN>
__global__ __launch_bounds__(512, 2)
void gemm1_k(const unsigned short* __restrict__ A, const unsigned short* __restrict__ B,
             unsigned short* __restrict__ Cb, const float* __restrict__ rw) {
  __shared__ __align__(1024) char lds[131072];
  constexpr int NT = KEXT / 64;
  const int tid = threadIdx.x;
  const int lane = tid & 63, wid = tid >> 6;
  const int wm = wid >> 2, wn = wid & 3;
  const int lr = lane & 15;

  const int nwg = gridDim.x, cpx = nwg >> 3;
  const int wg = (blockIdx.x & 7) * cpx + (blockIdx.x >> 3);
  const int bm = wg / NBN, bn = wg % NBN;

  const int swz = (lr & 7) << 4;
  const int colk0 = ((lane >> 4) * 16) ^ swz;
  const int colk1 = (64 + (lane >> 4) * 16) ^ swz;
  const int wmo = wm * 8192, wno = wn * 4096, lro = lr * 128;

  int aRow[2], aCol[2], bRow[2], bCol[2], o16[2];
  #pragma unroll
  for (int i = 0; i < 2; i++) {
    int o = (i * 512 + tid) * 16;
    o16[i] = o;
    { int wmb = o >> 13, ob = o & 8191, r = ob >> 7, cb = ob & 127;
      aRow[i] = wmb * 128 + r; aCol[i] = (cb ^ ((r & 7) << 4)) >> 1; }
    { int wnb = o >> 12, ob = o & 4095, r = ob >> 7, cb = ob & 127;
      bRow[i] = wnb * 64 + r; bCol[i] = (cb ^ ((r & 7) << 4)) >> 1; }
  }

  const unsigned short* Ag = A + (size_t)bm * 256 * LD;
  const unsigned short* Bg = B + (size_t)bn * 256 * LD;

  f32x4 acc[8][4];
  #pragma unroll
  for (int m = 0; m < 8; m++)
    #pragma unroll
    for (int n = 0; n < 4; n++) acc[m][n] = (f32x4){0.f, 0.f, 0.f, 0.f};

  char* const b0A = lds;
  char* const b1A = lds + 32768;
  char* const b0B = lds + 65536;
  char* const b1B = lds + 98304;

  // prologue: A0,B0 oldest; A1,B1 newest; vmcnt(4) leaves {A1,B1} in flight
  SU_A0(b0A, 0) SU_B0(b0B, 0)
  SU_A1(b0A, 0) SU_B1(b0B, 0)
  asm volatile("s_waitcnt vmcnt(4)" ::: "memory");
  __builtin_amdgcn_s_barrier();
  __builtin_amdgcn_sched_barrier(0);

  #pragma unroll 1
  for (int t = 0; t < NT; t += 2) {
    G1_TILE(b0A, b0B, b1A, b1B, (((t + 1) & (NT - 1)) << 6))
    G1_TILE(b1A, b1B, b0A, b0B, (((t + 2) & (NT - 1)) << 6))
  }

  asm volatile("s_waitcnt vmcnt(0)" ::: "memory");

  // epilogue: C/D layout col=lane&15, row=(lane>>4)*4+j (r4-verified mapping)
  const int jr = (lane >> 4) * 4;
  float wrow[8][4];
  #pragma unroll
  for (int m = 0; m < 8; m++)
    #pragma unroll
    for (int j = 0; j < 4; j++)
      wrow[m][j] = rw[(size_t)(bm * 256 + wm * 128 + m * 16 + jr + j) * 16 + bn];
  #pragma unroll
  for (int m = 0; m < 8; m++) {
    #pragma unroll
    for (int n = 0; n < 4; n++) {
      int col = bn * 256 + wn * 64 + n * 16 + lr;
      #pragma unroll
      for (int j = 0; j < 4; j++) {
        int r = bm * 256 + wm * 128 + m * 16 + jr + j;
        float v = acc[m][n][j];
        float g = 0.7978845608f * (v + 0.044715f * v * v * v);
        float e = __expf(2.f * g);
        float th = 1.f - 2.f / (e + 1.f);   // tanh(g), inf-safe
        float ge = 0.5f * v * (1.f + th);
        Cb[(size_t)r * NBIG + col] = f2bf(ge * wrow[m][j]);
      }
    }
  }
}

// ====== GEMM2: 128x256, 8-wave, 2-phase/K-tile, TRIPLE buffer (stage t+2) ======
// r6-verified reads (16/tile, minimal); NEW: 3 LDS slots, stage t+2 at P0,
// single vmcnt(6) at P1-end retires t+1's 6 loads (2-tile stage distance).
template <int K>
__global__ __launch_bounds__(512, 2)
void gemm2_k(const unsigned short* __restrict__ A, const unsigned short* __restrict__ B,
             float* __restrict__ Cf) {
  __shared__ __align__(1024) char lds[147456];
  constexpr int NT = K / 64;
  const int tid = threadIdx.x;
  const int lane = tid & 63, wid = tid >> 6;
  const int wm = wid >> 2, wn = wid & 3;   // 2 x 4 waves, wave tile 64x64
  const int lr = lane & 15;

  const int wg = (blockIdx.x & 7) * 32 + (blockIdx.x >> 3);  // nwg=256
  const int bm = wg >> 2, bn = wg & 3;

  const int swz = (lr & 7) << 4;
  const int colk0 = ((lane >> 4) * 16) ^ swz;
  const int colk1 = (64 + (lane >> 4) * 16) ^ swz;
  const int wmo = wm * 8192, wno = wn * 8192, lro = lr * 128;

  int aRow[2], aCol[2], o16[2];
  int bRow[4], bCol[4], o16b[4];
  #pragma unroll
  for (int i = 0; i < 2; i++) {
    int o = (i * 512 + tid) * 16;
    o16[i] = o;
    int r = o >> 7, cb = o & 127;
    aRow[i] = r; aCol[i] = (cb ^ ((r & 7) << 4)) >> 1;
  }
  #pragma unroll
  for (int i = 0; i < 4; i++) {
    int o = (i * 512 + tid) * 16;
    o16b[i] = o;
    int r = o >> 7, cb = o & 127;
    bRow[i] = r; bCol[i] = (cb ^ ((r & 7) << 4)) >> 1;
  }

  const unsigned short* Ag = A + (size_t)bm * 128 * K;
  const unsigned short* Bg = B + (size_t)bn * 256 * K;

  char* const ldsA = lds;            // 3 x 16384
  char* const ldsB = lds + 49152;    // 3 x 32768

  f32x4 acc[4][4];
  #pragma unroll
  for (int m = 0; m < 4; m++)
    #pragma unroll
    for (int n = 0; n < 4; n++) acc[m][n] = (f32x4){0.f, 0.f, 0.f, 0.f};

  // prologue: tile0 -> slot0 (oldest), tile1 -> slot1; vmcnt(6) retires tile0
  #pragma unroll
  for (int s = 0; s < 2; s++) {
    const int kk = s << 6;
    #pragma unroll
    for (int i = 0; i < 2; i++) async16(ldsA + s * 16384 + o16[i],  Ag + (size_t)aRow[i] * K + kk + aCol[i]);
    #pragma unroll
    for (int i = 0; i < 4; i++) async16(ldsB + s * 32768 + o16b[i], Bg + (size_t)bRow[i] * K + kk + bCol[i]);
  }
  asm volatile("s_waitcnt vmcnt(6)" ::: "memory");
  __builtin_amdgcn_s_barrier();
  __builtin_amdgcn_sched_barrier(0);

  int c0 = 0, c1 = 16384, c2 = 32768;   // A-slot byte offsets; B = 2x
  #pragma unroll 1
  for (int t = 0; t < NT; ++t) {
    const char* bufA = ldsA + c0;
    const char* bufB = ldsB + c0 * 2;
    char* wA = ldsA + c2;
    char* wB = ldsB + c2 * 2;
    const int kn = ((t + 2) & (NT - 1)) << 6;
    // P0: reads colk0 (8); stage all 6 units of tile t+2
    {
      bf16x8 afr[4], bfr[4];
      #pragma unroll
      for (int ml = 0; ml < 4; ml++)
        afr[ml] = *(const bf16x8*)(bufA + wmo + ml * 2048 + lro + colk0);
      #pragma unroll
      for (int nl = 0; nl < 4; nl++)
        bfr[nl] = *(const bf16x8*)(bufB + wno + nl * 2048 + lro + colk0);
      #pragma unroll
      for (int i = 0; i < 2; i++) async16(wA + o16[i],  Ag + (size_t)aRow[i] * K + kn + aCol[i]);
      #pragma unroll
      for (int i = 0; i < 4; i++) async16(wB + o16b[i], Bg + (size_t)bRow[i] * K + kn + bCol[i]);
      FENCE_PRE()
      #pragma unroll
      for (int m4 = 0; m4 < 4; m4++)
        #pragma unroll
        for (int n4 = 0; n4 < 4; n4++)
          acc[m4][n4] = MFMA16(afr[m4], bfr[n4], acc[m4][n4]);
      FENCE_POST_NOW()
    }
    // P1: reads colk1 (8); vmcnt(6) retires tile t+1's loads
    {
      bf16x8 afr[4], bfr[4];
      #pragma unroll
      for (int ml = 0; ml < 4; ml++)
        afr[ml] = *(const bf16x8*)(bufA + wmo + ml * 2048 + lro + colk1);
      #pragma unroll
      for (int nl = 0; nl < 4; nl++)
        bfr[nl] = *(const bf16x8*)(bufB + wno + nl * 2048 + lro + colk1);
      FENCE_PRE()
      #pragma unroll
      for (int m4 = 0; m4 < 4; m4++)
        #pragma unroll
        for (int n4 = 0; n4 < 4; n4++)
          acc[m4][n4] = MFMA16(afr[m4], bfr[n4], acc[m4][n4]);
      FENCE_POST_W6()
    }
    int tmp = c0; c0 = c1; c1 = c2; c2 = tmp;
  }

  asm volatile("s_waitcnt vmcnt(0)" ::: "memory");

  const int jr = (lane >> 4) * 4;
  #pragma unroll
  for (int m = 0; m < 4; m++) {
    #pragma unroll
    for (int n = 0; n < 4; n++) {
      int col = bn * 256 + wn * 64 + n * 16 + lr;
      #pragma unroll
      for (int j = 0; j < 4; j++) {
        int r = bm * 128 + wm * 64 + m * 16 + jr + j;
        Cf[(size_t)r * HID + col] = acc[m][n][j];
      }
    }
  }
}

extern "C" void kernel_launch(void* const* d_in, const int* in_sizes, int n_in,
                              void* d_out, int out_size, void* d_ws, size_t ws_size,
                              hipStream_t stream) {
  const float* x   = (const float*)d_in[0];
  const float* sm  = (const float*)d_in[1];
  const float* thr = (const float*)d_in[2];
  const float* w1  = (const float*)d_in[3];
  const float* w2  = (const float*)d_in[4];

  float* out_final  = (float*)d_out;
  float* out_scores = out_final + (size_t)NTOK * HID;
  float* out_k      = out_scores + (size_t)NTOK * NEXP;

  char* ws = (char*)d_ws;
  size_t off = 0;
  float* inv_smn = (float*)(ws + off); off += 256;
  float* rwbuf   = (float*)(ws + off); off += (size_t)NTOK * NEXP * 4;
  unsigned short* Xb  = (unsigned short*)(ws + off); off += (size_t)NTOK * HID * 2;
  unsigned short* W1T = (unsigned short*)(ws + off); off += (size_t)NBIG * HID * 2;
  unsigned short* W2T = (unsigned short*)(ws + off); off += (size_t)HID * NBIG * 2;
  unsigned short* H   = (unsigned short*)(ws + off); off += (size_t)NTOK * NBIG * 2;

  simnorm_kernel<<<1, 256, 0, stream>>>(sm, inv_smn);
  gate_kernel<<<NTOK, 256, 0, stream>>>(x, sm, thr, inv_smn, out_scores, out_k, rwbuf, Xb);
  transpose_cast_kernel<<<dim3(ISZ / 32, HID / 32, NEXP), 256, 0, stream>>>(
      w1, W1T, HID, ISZ, HID, HID * ISZ, ISZ * HID);
  transpose_cast_kernel<<<dim3(HID / 32, ISZ / 32, NEXP), 256, 0, stream>>>(
      w2, W2T, ISZ, HID, NBIG, ISZ * HID, ISZ);

  // H = gelu(Xb @ W1T^T) * rw   [8192 x 4096], 512 blocks
  gemm1_k<HID, HID, 16><<<512, 512, 0, stream>>>(Xb, W1T, H, rwbuf);
  // final = H @ W2T^T            [8192 x 1024], 256 blocks, triple-buffered
  gemm2_k<NBIG><<<256, 512, 0, stream>>>(H, W2T, out_final);
}